// Round 10
// baseline (200.504 us; speedup 1.0000x reference)
//
#include <hip/hip_runtime.h>
#include <hip/hip_bf16.h>

// CRF forward (log-partition) — B=1024, T=512, K=64.
// MFMA formulation: one wave handles GRP=16 batches. Exp-domain state
// U[64 tags × 16 batches], step: U <- (E·U) ∘ F, F = exp(emit - GBIAS).
//   - E = exp(trans) held as bf16 A-fragments (8 frags, 32 VGPRs)
//   - U held as bf16 B-fragments; MFMA C/D layout (col=lane&15,
//     row=4*(lane>>4)+reg, m89-verified) is k-compatible with the
//     B-fragment layout, so no cross-lane movement between steps.
//   - Same placement map κ(g,reg) used for E and U => result invariant
//     to the hardware's (lane,reg)->k mapping (permutation invariance).
//   - Per-column rescale every 8 steps (C accumulates logs off-chain);
//     per-column finish event at t == len-1 snapshots the column LSE.
// No LDS, no barriers, no broadcasts — the R2..R8 serial-chain killers.
// R9 compile fixes: pkbf via v_cvt_pk_bf16_f32 inline asm (bf162 is not
// trivially copyable for bit_cast); STEP terminates RES with ';'.

constexpr int CRF_B = 1024;
constexpr int CRF_T = 512;
constexpr int CRF_K = 64;
constexpr int GRP   = 16;

#define GBIAS 4.5f
#define L2E   1.4426950408889634f

typedef short        s8v __attribute__((ext_vector_type(8)));
typedef float        f4v __attribute__((ext_vector_type(4)));
typedef unsigned int u4v __attribute__((ext_vector_type(4)));

__device__ __forceinline__ unsigned short f2bf_rn(float f) { // init-only cvt
    unsigned int u = __float_as_uint(f);
    return (unsigned short)((u + 0x7fffu + ((u >> 16) & 1u)) >> 16);
}
__device__ __forceinline__ unsigned int pkbf(float lo, float hi) {
    unsigned int r;                       // r.lo16 = bf16(lo), r.hi16 = bf16(hi)
    asm("v_cvt_pk_bf16_f32 %0, %1, %2" : "=v"(r) : "v"(lo), "v"(hi));
    return r;
}

#define MF(Aop, Bop, Cop) \
    __builtin_amdgcn_mfma_f32_16x16x32_bf16(Aop, Bop, Cop, 0, 0, 0)

// Rebuild B-fragments from f32 state u0..u3 (tiles 0..3).
// Bf0 regs: [0..3]=tile0 (k=4g+r), [4..7]=tile1 (k=16+4g+r); Bf1: tiles 2,3.
#define PACKB() do {                                                   \
    u4v w0_, w1_;                                                      \
    w0_[0] = pkbf(u0[0], u0[1]);  w0_[1] = pkbf(u0[2], u0[3]);         \
    w0_[2] = pkbf(u1[0], u1[1]);  w0_[3] = pkbf(u1[2], u1[3]);         \
    w1_[0] = pkbf(u2[0], u2[1]);  w1_[1] = pkbf(u2[2], u2[3]);         \
    w1_[2] = pkbf(u3[0], u3[1]);  w1_[3] = pkbf(u3[2], u3[3]);         \
    Bf0 = __builtin_bit_cast(s8v, w0_);                                \
    Bf1 = __builtin_bit_cast(s8v, w1_);                                \
} while (0)

// Column-finish event: out[b] = CC + GBIAS*t + log(sum_i U[i,col]).
#define FINISH(tt) do {                                                \
    f4v sv_ = (u0 + u1) + (u2 + u3);                                   \
    float s_ = (sv_[0] + sv_[1]) + (sv_[2] + sv_[3]);                  \
    s_ += __shfl_xor(s_, 16, 64);                                      \
    s_ += __shfl_xor(s_, 32, 64);                                      \
    float res_ = CC + GBIAS * (float)(tt) + __logf(s_);                \
    if (((tt) == lenm1) && lane < 16) out[b0 + lane] = res_;           \
} while (0)

// Per-column rescale (column = lanes {c, c+16, c+32, c+48}).
#define RESCALE do {                                                   \
    f4v mv_ = __builtin_elementwise_max(                               \
        __builtin_elementwise_max(u0, u1),                             \
        __builtin_elementwise_max(u2, u3));                            \
    float m_ = fmaxf(fmaxf(mv_[0], mv_[1]), fmaxf(mv_[2], mv_[3]));    \
    m_ = fmaxf(m_, __shfl_xor(m_, 16, 64));                            \
    m_ = fmaxf(m_, __shfl_xor(m_, 32, 64));                            \
    float r_ = __builtin_amdgcn_rcpf(m_);                              \
    CC += __logf(m_);                                                  \
    u0 *= r_; u1 *= r_; u2 *= r_; u3 *= r_;                            \
} while (0)

// Prefetch a 4-step emission set (clamped per column to its own length).
#define LOADSET(P, tbase) do {                                         \
    int ro_;                                                           \
    ro_ = min((tbase) + 0, lenm1) * CRF_K;                             \
    P##00 = *(const f4v*)(fbl + ro_);      P##01 = *(const f4v*)(fbl + ro_ + 16); \
    P##02 = *(const f4v*)(fbl + ro_ + 32); P##03 = *(const f4v*)(fbl + ro_ + 48); \
    ro_ = min((tbase) + 1, lenm1) * CRF_K;                             \
    P##10 = *(const f4v*)(fbl + ro_);      P##11 = *(const f4v*)(fbl + ro_ + 16); \
    P##12 = *(const f4v*)(fbl + ro_ + 32); P##13 = *(const f4v*)(fbl + ro_ + 48); \
    ro_ = min((tbase) + 2, lenm1) * CRF_K;                             \
    P##20 = *(const f4v*)(fbl + ro_);      P##21 = *(const f4v*)(fbl + ro_ + 16); \
    P##22 = *(const f4v*)(fbl + ro_ + 32); P##23 = *(const f4v*)(fbl + ro_ + 48); \
    ro_ = min((tbase) + 3, lenm1) * CRF_K;                             \
    P##30 = *(const f4v*)(fbl + ro_);      P##31 = *(const f4v*)(fbl + ro_ + 16); \
    P##32 = *(const f4v*)(fbl + ro_ + 32); P##33 = *(const f4v*)(fbl + ro_ + 48); \
} while (0)

// One step: 8 MFMA + F (16 exp2) + mul + finish-check [+ rescale] + repack.
#define STEP(P, s, tt, RES) do {                                       \
    f4v a0 = MF(A00, Bf0, kZ); a0 = MF(A01, Bf1, a0);                  \
    f4v a1 = MF(A10, Bf0, kZ); a1 = MF(A11, Bf1, a1);                  \
    f4v a2 = MF(A20, Bf0, kZ); a2 = MF(A21, Bf1, a2);                  \
    f4v a3 = MF(A30, Bf0, kZ); a3 = MF(A31, Bf1, a3);                  \
    f4v g0_ = __builtin_elementwise_fma(P##s##0, kL2E4, kNG4);         \
    f4v g1_ = __builtin_elementwise_fma(P##s##1, kL2E4, kNG4);         \
    f4v g2_ = __builtin_elementwise_fma(P##s##2, kL2E4, kNG4);         \
    f4v g3_ = __builtin_elementwise_fma(P##s##3, kL2E4, kNG4);         \
    f4v F0_, F1_, F2_, F3_;                                            \
    F0_[0]=exp2f(g0_[0]); F0_[1]=exp2f(g0_[1]); F0_[2]=exp2f(g0_[2]); F0_[3]=exp2f(g0_[3]); \
    F1_[0]=exp2f(g1_[0]); F1_[1]=exp2f(g1_[1]); F1_[2]=exp2f(g1_[2]); F1_[3]=exp2f(g1_[3]); \
    F2_[0]=exp2f(g2_[0]); F2_[1]=exp2f(g2_[1]); F2_[2]=exp2f(g2_[2]); F2_[3]=exp2f(g2_[3]); \
    F3_[0]=exp2f(g3_[0]); F3_[1]=exp2f(g3_[1]); F3_[2]=exp2f(g3_[2]); F3_[3]=exp2f(g3_[3]); \
    u0 = a0 * F0_; u1 = a1 * F1_; u2 = a2 * F2_; u3 = a3 * F3_;        \
    if (__any((tt) == lenm1)) { FINISH(tt); }                          \
    RES;                                                               \
    PACKB();                                                           \
} while (0)

__global__ __launch_bounds__(64)
__attribute__((amdgpu_waves_per_eu(1, 1)))
void crf_forward_kernel(
    const float* __restrict__ feats,      // [B, T, K]
    const float* __restrict__ trans,      // [K, K]
    const int*   __restrict__ seq_lens,   // [B]
    float*       __restrict__ out)        // [B]
{
    const int lane = threadIdx.x;
    const int gq   = lane >> 4;           // 4-lane group (k/row sub-index)
    const int c    = lane & 15;           // column: batch (B/C) | row m (A)
    const int b0   = blockIdx.x * GRP;

    const f4v kZ    = {0.f, 0.f, 0.f, 0.f};
    const f4v kL2E4 = {L2E, L2E, L2E, L2E};
    const f4v kNG4  = {-GBIAS * L2E, -GBIAS * L2E, -GBIAS * L2E, -GBIAS * L2E};

    // E A-fragments: A(mb,n) element reg holds E[16mb + c][32n + kappa(g,reg)],
    // kappa(g,reg) = 4g+reg (reg<4) | 16+4g+(reg-4). Same kappa used in PACKB.
    auto ldE = [&](int mb, int n) {
        s8v f;
#pragma unroll
        for (int reg = 0; reg < 8; ++reg) {
            int k = (reg < 4) ? (4 * gq + reg) : (16 + 4 * gq + (reg - 4));
            float v = __expf(trans[(16 * mb + c) * CRF_K + 32 * n + k]);
            f[reg] = (short)f2bf_rn(v);
        }
        return f;
    };
    const s8v A00 = ldE(0, 0), A01 = ldE(0, 1);
    const s8v A10 = ldE(1, 0), A11 = ldE(1, 1);
    const s8v A20 = ldE(2, 0), A21 = ldE(2, 1);
    const s8v A30 = ldE(3, 0), A31 = ldE(3, 1);

    const int lenm1 = seq_lens[b0 + c] - 1;         // per-lane (column) length
    int mx = lenm1;
#pragma unroll
    for (int off = 1; off < 64; off <<= 1) mx = max(mx, __shfl_xor(mx, off, 64));
    const int Lg = __builtin_amdgcn_readfirstlane(mx) + 1;   // group max len

    const float* fbl = feats + (size_t)(b0 + c) * (CRF_T * CRF_K) + 4 * gq;

    // t = 0: U = exp(emit0 - GBIAS) in C/D layout; alpha = CC + GBIAS*t + log U.
    f4v u0, u1, u2, u3;
    s8v Bf0, Bf1;
    {
        const f4v e0 = *(const f4v*)(fbl);
        const f4v e1 = *(const f4v*)(fbl + 16);
        const f4v e2 = *(const f4v*)(fbl + 32);
        const f4v e3 = *(const f4v*)(fbl + 48);
#pragma unroll
        for (int j = 0; j < 4; ++j) {
            u0[j] = __expf(e0[j] - GBIAS); u1[j] = __expf(e1[j] - GBIAS);
            u2[j] = __expf(e2[j] - GBIAS); u3[j] = __expf(e3[j] - GBIAS);
        }
    }
    float CC = GBIAS;
    if (__any(0 == lenm1)) { FINISH(0); }
    PACKB();

    // Prefetch regs: two ping-pong sets of 4 steps x 4 tiles (128 VGPRs).
    f4v PA00, PA01, PA02, PA03, PA10, PA11, PA12, PA13,
        PA20, PA21, PA22, PA23, PA30, PA31, PA32, PA33;
    f4v PB00, PB01, PB02, PB03, PB10, PB11, PB12, PB13,
        PB20, PB21, PB22, PB23, PB30, PB31, PB32, PB33;

    LOADSET(PA, 1);
    for (int tb = 1; tb < Lg; tb += 8) {
        LOADSET(PB, tb + 4);
        STEP(PA, 0, tb + 0, );
        STEP(PA, 1, tb + 1, );
        STEP(PA, 2, tb + 2, );
        STEP(PA, 3, tb + 3, );
        LOADSET(PA, tb + 8);
        STEP(PB, 0, tb + 4, );
        STEP(PB, 1, tb + 5, );
        STEP(PB, 2, tb + 6, );
        STEP(PB, 3, tb + 7, RESCALE);
    }
}

extern "C" void kernel_launch(void* const* d_in, const int* in_sizes, int n_in,
                              void* d_out, int out_size, void* d_ws, size_t ws_size,
                              hipStream_t stream)
{
    const float* feats    = (const float*)d_in[0];
    const float* trans    = (const float*)d_in[1];
    const int*   seq_lens = (const int*)d_in[2];
    float*       out      = (float*)d_out;

    crf_forward_kernel<<<dim3(CRF_B / GRP), dim3(64), 0, stream>>>(
        feats, trans, seq_lens, out);
}

// Round 11
// 199.042 us; speedup vs baseline: 1.0073x; 1.0073x over previous
//
#include <hip/hip_runtime.h>
#include <hip/hip_bf16.h>

// CRF forward (log-partition) — B=1024, T=512, K=64.
// MFMA formulation: one wave handles GRP=16 batches. Exp-domain state
// U[64 tags × 16 batches], step: U <- (E·U) ∘ F, F = exp(emit - GBIAS).
// R10 lesson: compiler sank the register prefetch to its uses (VGPR=132 vs
// ~250 needed) -> every step ate ~900 cy of HBM latency on the chain.
// This round: emission prefetch via VOLATILE inline-asm global_load_dwordx4
// (cannot be sunk or rematerialized) + counted s_waitcnt vmcnt(16) pinned
// AFTER the other set's issue, carrying the consumed set as "+v" operands.
// Each 16-load set's latency hides under ~4 steps of MFMA+VALU compute.

constexpr int CRF_B = 1024;
constexpr int CRF_T = 512;
constexpr int CRF_K = 64;
constexpr int GRP   = 16;

#define GBIAS 4.5f
#define L2E   1.4426950408889634f

typedef short        s8v __attribute__((ext_vector_type(8)));
typedef float        f4v __attribute__((ext_vector_type(4)));
typedef unsigned int u4v __attribute__((ext_vector_type(4)));

__device__ __forceinline__ unsigned short f2bf_rn(float f) { // init-only cvt
    unsigned int u = __float_as_uint(f);
    return (unsigned short)((u + 0x7fffu + ((u >> 16) & 1u)) >> 16);
}
__device__ __forceinline__ unsigned int pkbf(float lo, float hi) {
    unsigned int r;                       // r.lo16 = bf16(lo), r.hi16 = bf16(hi)
    asm("v_cvt_pk_bf16_f32 %0, %1, %2" : "=v"(r) : "v"(lo), "v"(hi));
    return r;
}

#define MF(Aop, Bop, Cop) \
    __builtin_amdgcn_mfma_f32_16x16x32_bf16(Aop, Bop, Cop, 0, 0, 0)

// Rebuild B-fragments from f32 state u0..u3 (tiles 0..3).
#define PACKB() do {                                                   \
    u4v w0_, w1_;                                                      \
    w0_[0] = pkbf(u0[0], u0[1]);  w0_[1] = pkbf(u0[2], u0[3]);         \
    w0_[2] = pkbf(u1[0], u1[1]);  w0_[3] = pkbf(u1[2], u1[3]);         \
    w1_[0] = pkbf(u2[0], u2[1]);  w1_[1] = pkbf(u2[2], u2[3]);         \
    w1_[2] = pkbf(u3[0], u3[1]);  w1_[3] = pkbf(u3[2], u3[3]);         \
    Bf0 = __builtin_bit_cast(s8v, w0_);                                \
    Bf1 = __builtin_bit_cast(s8v, w1_);                                \
} while (0)

// Column-finish event: out[b] = CC + GBIAS*t + log(sum_i U[i,col]).
#define FINISH(tt) do {                                                \
    f4v sv_ = (u0 + u1) + (u2 + u3);                                   \
    float s_ = (sv_[0] + sv_[1]) + (sv_[2] + sv_[3]);                  \
    s_ += __shfl_xor(s_, 16, 64);                                      \
    s_ += __shfl_xor(s_, 32, 64);                                      \
    float res_ = CC + GBIAS * (float)(tt) + __logf(s_);                \
    if (((tt) == lenm1) && lane < 16) out[b0 + lane] = res_;           \
} while (0)

// Per-column rescale (column = lanes {c, c+16, c+32, c+48}).
#define RESCALE do {                                                   \
    f4v mv_ = __builtin_elementwise_max(                               \
        __builtin_elementwise_max(u0, u1),                             \
        __builtin_elementwise_max(u2, u3));                            \
    float m_ = fmaxf(fmaxf(mv_[0], mv_[1]), fmaxf(mv_[2], mv_[3]));    \
    m_ = fmaxf(m_, __shfl_xor(m_, 16, 64));                            \
    m_ = fmaxf(m_, __shfl_xor(m_, 32, 64));                            \
    float r_ = __builtin_amdgcn_rcpf(m_);                              \
    CC += __logf(m_);                                                  \
    u0 *= r_; u1 *= r_; u2 *= r_; u3 *= r_;                            \
} while (0)

// Volatile asm load: cannot be sunk/rematerialized; 4 loads share one addr.
#define LDX4(dst, p, off) \
    asm volatile("global_load_dwordx4 %0, %1, off offset:" #off \
                 : "=v"(dst) : "v"(p))

// Issue a 4-step emission set (16 loads), clamped per column.
#define LOADSET(P, tbase) do {                                          \
    const float* rp0_ = fbl + (size_t)min((tbase) + 0, lenm1) * CRF_K;  \
    const float* rp1_ = fbl + (size_t)min((tbase) + 1, lenm1) * CRF_K;  \
    const float* rp2_ = fbl + (size_t)min((tbase) + 2, lenm1) * CRF_K;  \
    const float* rp3_ = fbl + (size_t)min((tbase) + 3, lenm1) * CRF_K;  \
    LDX4(P##00, rp0_, 0);  LDX4(P##01, rp0_, 64);                       \
    LDX4(P##02, rp0_, 128); LDX4(P##03, rp0_, 192);                     \
    LDX4(P##10, rp1_, 0);  LDX4(P##11, rp1_, 64);                       \
    LDX4(P##12, rp1_, 128); LDX4(P##13, rp1_, 192);                     \
    LDX4(P##20, rp2_, 0);  LDX4(P##21, rp2_, 64);                       \
    LDX4(P##22, rp2_, 128); LDX4(P##23, rp2_, 192);                     \
    LDX4(P##30, rp3_, 0);  LDX4(P##31, rp3_, 64);                       \
    LDX4(P##32, rp3_, 128); LDX4(P##33, rp3_, 192);                     \
} while (0)

// Counted wait: the other set's 16 loads may remain in flight. Pins the
// consumed set's registers so no use can be hoisted above the wait.
#define WAITSET(P)                                                      \
    asm volatile("s_waitcnt vmcnt(16)"                                  \
        : "+v"(P##00), "+v"(P##01), "+v"(P##02), "+v"(P##03),           \
          "+v"(P##10), "+v"(P##11), "+v"(P##12), "+v"(P##13),           \
          "+v"(P##20), "+v"(P##21), "+v"(P##22), "+v"(P##23),           \
          "+v"(P##30), "+v"(P##31), "+v"(P##32), "+v"(P##33))

// One step: 8 MFMA + F (16 exp2) + mul + finish-check [+ rescale] + repack.
#define STEP(P, s, tt, RES) do {                                       \
    f4v a0 = MF(A00, Bf0, kZ); a0 = MF(A01, Bf1, a0);                  \
    f4v a1 = MF(A10, Bf0, kZ); a1 = MF(A11, Bf1, a1);                  \
    f4v a2 = MF(A20, Bf0, kZ); a2 = MF(A21, Bf1, a2);                  \
    f4v a3 = MF(A30, Bf0, kZ); a3 = MF(A31, Bf1, a3);                  \
    f4v g0_ = __builtin_elementwise_fma(P##s##0, kL2E4, kNG4);         \
    f4v g1_ = __builtin_elementwise_fma(P##s##1, kL2E4, kNG4);         \
    f4v g2_ = __builtin_elementwise_fma(P##s##2, kL2E4, kNG4);         \
    f4v g3_ = __builtin_elementwise_fma(P##s##3, kL2E4, kNG4);         \
    f4v F0_, F1_, F2_, F3_;                                            \
    F0_[0]=exp2f(g0_[0]); F0_[1]=exp2f(g0_[1]); F0_[2]=exp2f(g0_[2]); F0_[3]=exp2f(g0_[3]); \
    F1_[0]=exp2f(g1_[0]); F1_[1]=exp2f(g1_[1]); F1_[2]=exp2f(g1_[2]); F1_[3]=exp2f(g1_[3]); \
    F2_[0]=exp2f(g2_[0]); F2_[1]=exp2f(g2_[1]); F2_[2]=exp2f(g2_[2]); F2_[3]=exp2f(g2_[3]); \
    F3_[0]=exp2f(g3_[0]); F3_[1]=exp2f(g3_[1]); F3_[2]=exp2f(g3_[2]); F3_[3]=exp2f(g3_[3]); \
    u0 = a0 * F0_; u1 = a1 * F1_; u2 = a2 * F2_; u3 = a3 * F3_;        \
    if (__any((tt) == lenm1)) { FINISH(tt); }                          \
    RES;                                                               \
    PACKB();                                                           \
} while (0)

__global__ __launch_bounds__(64)
__attribute__((amdgpu_waves_per_eu(1, 1)))
void crf_forward_kernel(
    const float* __restrict__ feats,      // [B, T, K]
    const float* __restrict__ trans,      // [K, K]
    const int*   __restrict__ seq_lens,   // [B]
    float*       __restrict__ out)        // [B]
{
    const int lane = threadIdx.x;
    const int gq   = lane >> 4;           // 4-lane group (k/row sub-index)
    const int c    = lane & 15;           // column: batch (B/C) | row m (A)
    const int b0   = blockIdx.x * GRP;

    const f4v kZ    = {0.f, 0.f, 0.f, 0.f};
    const f4v kL2E4 = {L2E, L2E, L2E, L2E};
    const f4v kNG4  = {-GBIAS * L2E, -GBIAS * L2E, -GBIAS * L2E, -GBIAS * L2E};

    // E A-fragments: A(mb,n) reg holds E[16mb + c][32n + kappa(g,reg)],
    // kappa(g,reg) = 4g+reg (reg<4) | 16+4g+(reg-4). Same kappa in PACKB.
    auto ldE = [&](int mb, int n) {
        s8v f;
#pragma unroll
        for (int reg = 0; reg < 8; ++reg) {
            int k = (reg < 4) ? (4 * gq + reg) : (16 + 4 * gq + (reg - 4));
            float v = __expf(trans[(16 * mb + c) * CRF_K + 32 * n + k]);
            f[reg] = (short)f2bf_rn(v);
        }
        return f;
    };
    const s8v A00 = ldE(0, 0), A01 = ldE(0, 1);
    const s8v A10 = ldE(1, 0), A11 = ldE(1, 1);
    const s8v A20 = ldE(2, 0), A21 = ldE(2, 1);
    const s8v A30 = ldE(3, 0), A31 = ldE(3, 1);

    const int lenm1 = seq_lens[b0 + c] - 1;         // per-lane (column) length
    int mx = lenm1;
#pragma unroll
    for (int off = 1; off < 64; off <<= 1) mx = max(mx, __shfl_xor(mx, off, 64));
    const int Lg = __builtin_amdgcn_readfirstlane(mx) + 1;   // group max len

    const float* fbl = feats + (size_t)(b0 + c) * (CRF_T * CRF_K) + 4 * gq;

    // t = 0: U = exp(emit0 - GBIAS) in C/D layout.
    f4v u0, u1, u2, u3;
    s8v Bf0, Bf1;
    {
        const f4v e0 = *(const f4v*)(fbl);
        const f4v e1 = *(const f4v*)(fbl + 16);
        const f4v e2 = *(const f4v*)(fbl + 32);
        const f4v e3 = *(const f4v*)(fbl + 48);
#pragma unroll
        for (int j = 0; j < 4; ++j) {
            u0[j] = __expf(e0[j] - GBIAS); u1[j] = __expf(e1[j] - GBIAS);
            u2[j] = __expf(e2[j] - GBIAS); u3[j] = __expf(e3[j] - GBIAS);
        }
    }
    float CC = GBIAS;
    if (__any(0 == lenm1)) { FINISH(0); }
    PACKB();

    // Ping-pong prefetch sets, 4 steps x 4 tiles each, asm-pinned.
    f4v PA00, PA01, PA02, PA03, PA10, PA11, PA12, PA13,
        PA20, PA21, PA22, PA23, PA30, PA31, PA32, PA33;
    f4v PB00, PB01, PB02, PB03, PB10, PB11, PB12, PB13,
        PB20, PB21, PB22, PB23, PB30, PB31, PB32, PB33;

    LOADSET(PA, 1);
    for (int tb = 1; tb < Lg; tb += 8) {
        LOADSET(PB, tb + 4);              // 16 newer loads in flight
        WAITSET(PA);                      // vmcnt(16): PA arrived
        STEP(PA, 0, tb + 0, );
        STEP(PA, 1, tb + 1, );
        STEP(PA, 2, tb + 2, );
        STEP(PA, 3, tb + 3, );
        LOADSET(PA, tb + 8);
        WAITSET(PB);                      // vmcnt(16): PB arrived
        STEP(PB, 0, tb + 4, );
        STEP(PB, 1, tb + 5, );
        STEP(PB, 2, tb + 6, );
        STEP(PB, 3, tb + 7, RESCALE);
    }
    asm volatile("s_waitcnt vmcnt(0)" ::: "memory");  // drain before endpgm
}

extern "C" void kernel_launch(void* const* d_in, const int* in_sizes, int n_in,
                              void* d_out, int out_size, void* d_ws, size_t ws_size,
                              hipStream_t stream)
{
    const float* feats    = (const float*)d_in[0];
    const float* trans    = (const float*)d_in[1];
    const int*   seq_lens = (const int*)d_in[2];
    float*       out      = (float*)d_out;

    crf_forward_kernel<<<dim3(CRF_B / GRP), dim3(64), 0, stream>>>(
        feats, trans, seq_lens, out);
}

// Round 12
// 183.763 us; speedup vs baseline: 1.0911x; 1.0831x over previous
//
#include <hip/hip_runtime.h>
#include <hip/hip_bf16.h>

// CRF forward (log-partition) — B=1024, T=512, K=64.
// MFMA engine (R10, numerics verified) + full parallelism (R2..R6 style):
// ONE SEQUENCE PER WAVE, tags replicated across the 16 MFMA columns.
//   state U[64 tags] as exp-domain f32, replicated in all 16 cols;
//   step: U <- (E·U) ∘ F, via 8x mfma_f32_16x16x32_bf16 (cols replicated
//   => C/D stays replicated; C/D row layout == B-fragment k layout under
//   the shared kappa(g,reg) map => recurrence closes in-register).
// No LDS / shuffle / readlane / broadcast anywhere in the loop.
// R11 lesson: 64 waves on 1024 SIMDs (0.68% occupancy) was the killer,
// not load scheduling. Now: 1024 waves, each runs exactly its own length,
// lenm1 is wave-uniform (no per-step __any / FINISH checks).

constexpr int CRF_B = 1024;
constexpr int CRF_T = 512;
constexpr int CRF_K = 64;

#define GBIAS 4.5f
#define L2E   1.4426950408889634f

typedef short        s8v __attribute__((ext_vector_type(8)));
typedef float        f4v __attribute__((ext_vector_type(4)));
typedef unsigned int u4v __attribute__((ext_vector_type(4)));

__device__ __forceinline__ unsigned short f2bf_rn(float f) { // init-only cvt
    unsigned int u = __float_as_uint(f);
    return (unsigned short)((u + 0x7fffu + ((u >> 16) & 1u)) >> 16);
}
__device__ __forceinline__ unsigned int pkbf(float lo, float hi) {
    unsigned int r;                       // lo16 = bf16(lo), hi16 = bf16(hi)
    asm("v_cvt_pk_bf16_f32 %0, %1, %2" : "=v"(r) : "v"(lo), "v"(hi));
    return r;
}

#define MF(Aop, Bop, Cop) \
    __builtin_amdgcn_mfma_f32_16x16x32_bf16(Aop, Bop, Cop, 0, 0, 0)

// Rebuild B-fragments from f32 state u0..u3 (k-tiles 0..3).
#define PACKB() do {                                                   \
    u4v w0_, w1_;                                                      \
    w0_[0] = pkbf(u0[0], u0[1]);  w0_[1] = pkbf(u0[2], u0[3]);         \
    w0_[2] = pkbf(u1[0], u1[1]);  w0_[3] = pkbf(u1[2], u1[3]);         \
    w1_[0] = pkbf(u2[0], u2[1]);  w1_[1] = pkbf(u2[2], u2[3]);         \
    w1_[2] = pkbf(u3[0], u3[1]);  w1_[3] = pkbf(u3[2], u3[3]);         \
    Bf0 = __builtin_bit_cast(s8v, w0_);                                \
    Bf1 = __builtin_bit_cast(s8v, w1_);                                \
} while (0)

// Rescale: max over this lane's 16 rows + across the 4 gq groups.
#define RESCALE do {                                                   \
    f4v mv_ = __builtin_elementwise_max(                               \
        __builtin_elementwise_max(u0, u1),                             \
        __builtin_elementwise_max(u2, u3));                            \
    float m_ = fmaxf(fmaxf(mv_[0], mv_[1]), fmaxf(mv_[2], mv_[3]));    \
    m_ = fmaxf(m_, __shfl_xor(m_, 16, 64));                            \
    m_ = fmaxf(m_, __shfl_xor(m_, 32, 64));                            \
    float r_ = __builtin_amdgcn_rcpf(m_);                              \
    CC += __logf(m_);                                                  \
    u0 *= r_; u1 *= r_; u2 *= r_; u3 *= r_;                            \
} while (0)

// Volatile asm load: cannot be sunk/rematerialized.
#define LDX4(dst, p, off) \
    asm volatile("global_load_dwordx4 %0, %1, off offset:" #off \
                 : "=v"(dst) : "v"(p))

// Issue a 4-step emission set (16 loads). tbase/lenm1 are wave-uniform.
#define LOADSET(P, tbase) do {                                          \
    const float* rp0_ = fbl + (size_t)min((tbase) + 0, lenm1) * CRF_K;  \
    const float* rp1_ = fbl + (size_t)min((tbase) + 1, lenm1) * CRF_K;  \
    const float* rp2_ = fbl + (size_t)min((tbase) + 2, lenm1) * CRF_K;  \
    const float* rp3_ = fbl + (size_t)min((tbase) + 3, lenm1) * CRF_K;  \
    LDX4(P##00, rp0_, 0);  LDX4(P##01, rp0_, 64);                       \
    LDX4(P##02, rp0_, 128); LDX4(P##03, rp0_, 192);                     \
    LDX4(P##10, rp1_, 0);  LDX4(P##11, rp1_, 64);                       \
    LDX4(P##12, rp1_, 128); LDX4(P##13, rp1_, 192);                     \
    LDX4(P##20, rp2_, 0);  LDX4(P##21, rp2_, 64);                       \
    LDX4(P##22, rp2_, 128); LDX4(P##23, rp2_, 192);                     \
    LDX4(P##30, rp3_, 0);  LDX4(P##31, rp3_, 64);                       \
    LDX4(P##32, rp3_, 128); LDX4(P##33, rp3_, 192);                     \
} while (0)

// Counted waits pinning the consumed set's registers.
#define WAITSET_N(P, n)                                                 \
    asm volatile("s_waitcnt vmcnt(" #n ")"                              \
        : "+v"(P##00), "+v"(P##01), "+v"(P##02), "+v"(P##03),           \
          "+v"(P##10), "+v"(P##11), "+v"(P##12), "+v"(P##13),           \
          "+v"(P##20), "+v"(P##21), "+v"(P##22), "+v"(P##23),           \
          "+v"(P##30), "+v"(P##31), "+v"(P##32), "+v"(P##33))

// One step: 8 MFMA + F (16 exp2) + mul [+ rescale] + repack. No checks.
#define STEP(P, s, RES) do {                                           \
    f4v a0 = MF(A00, Bf0, kZ); a0 = MF(A01, Bf1, a0);                  \
    f4v a1 = MF(A10, Bf0, kZ); a1 = MF(A11, Bf1, a1);                  \
    f4v a2 = MF(A20, Bf0, kZ); a2 = MF(A21, Bf1, a2);                  \
    f4v a3 = MF(A30, Bf0, kZ); a3 = MF(A31, Bf1, a3);                  \
    f4v g0_ = __builtin_elementwise_fma(P##s##0, kL2E4, kNG4);         \
    f4v g1_ = __builtin_elementwise_fma(P##s##1, kL2E4, kNG4);         \
    f4v g2_ = __builtin_elementwise_fma(P##s##2, kL2E4, kNG4);         \
    f4v g3_ = __builtin_elementwise_fma(P##s##3, kL2E4, kNG4);         \
    f4v F0_, F1_, F2_, F3_;                                            \
    F0_[0]=exp2f(g0_[0]); F0_[1]=exp2f(g0_[1]); F0_[2]=exp2f(g0_[2]); F0_[3]=exp2f(g0_[3]); \
    F1_[0]=exp2f(g1_[0]); F1_[1]=exp2f(g1_[1]); F1_[2]=exp2f(g1_[2]); F1_[3]=exp2f(g1_[3]); \
    F2_[0]=exp2f(g2_[0]); F2_[1]=exp2f(g2_[1]); F2_[2]=exp2f(g2_[2]); F2_[3]=exp2f(g2_[3]); \
    F3_[0]=exp2f(g3_[0]); F3_[1]=exp2f(g3_[1]); F3_[2]=exp2f(g3_[2]); F3_[3]=exp2f(g3_[3]); \
    u0 = a0 * F0_; u1 = a1 * F1_; u2 = a2 * F2_; u3 = a3 * F3_;        \
    RES;                                                               \
    PACKB();                                                           \
} while (0)

__global__ __launch_bounds__(64)
__attribute__((amdgpu_waves_per_eu(1, 1)))
void crf_forward_kernel(
    const float* __restrict__ feats,      // [B, T, K]
    const float* __restrict__ trans,      // [K, K]
    const int*   __restrict__ seq_lens,   // [B]
    float*       __restrict__ out)        // [B]
{
    const int lane = threadIdx.x;
    const int gq   = lane >> 4;           // k/row sub-index (4-lane group)
    const int c    = lane & 15;           // A row (m) | replicated B/C column
    const int b    = blockIdx.x;          // ONE sequence per wave

    const f4v kZ    = {0.f, 0.f, 0.f, 0.f};
    const f4v kL2E4 = {L2E, L2E, L2E, L2E};
    const f4v kNG4  = {-GBIAS * L2E, -GBIAS * L2E, -GBIAS * L2E, -GBIAS * L2E};

    // E A-fragments: A(mb,n) reg holds E[16mb + c][32n + kappa(gq,reg)],
    // kappa = 4gq+reg (reg<4) | 16+4gq+(reg-4). Same kappa in PACKB.
    auto ldE = [&](int mb, int n) {
        s8v f;
#pragma unroll
        for (int reg = 0; reg < 8; ++reg) {
            int k = (reg < 4) ? (4 * gq + reg) : (16 + 4 * gq + (reg - 4));
            float v = __expf(trans[(16 * mb + c) * CRF_K + 32 * n + k]);
            f[reg] = (short)f2bf_rn(v);
        }
        return f;
    };
    const s8v A00 = ldE(0, 0), A01 = ldE(0, 1);
    const s8v A10 = ldE(1, 0), A11 = ldE(1, 1);
    const s8v A20 = ldE(2, 0), A21 = ldE(2, 1);
    const s8v A30 = ldE(3, 0), A31 = ldE(3, 1);

    const int lenm1 = seq_lens[b] - 1;    // WAVE-UNIFORM now
    const int L     = lenm1 + 1;

    // Lane address depends only on gq: 16 lanes/addr, L2 broadcasts.
    const float* fbl = feats + (size_t)b * (CRF_T * CRF_K) + 4 * gq;

    // t = 0: U = exp(emit0 - GBIAS), replicated across columns.
    f4v u0, u1, u2, u3;
    s8v Bf0, Bf1;
    {
        const f4v e0 = *(const f4v*)(fbl);
        const f4v e1 = *(const f4v*)(fbl + 16);
        const f4v e2 = *(const f4v*)(fbl + 32);
        const f4v e3 = *(const f4v*)(fbl + 48);
#pragma unroll
        for (int j = 0; j < 4; ++j) {
            u0[j] = __expf(e0[j] - GBIAS); u1[j] = __expf(e1[j] - GBIAS);
            u2[j] = __expf(e2[j] - GBIAS); u3[j] = __expf(e3[j] - GBIAS);
        }
    }
    float CC = GBIAS;
    PACKB();

    f4v PA00, PA01, PA02, PA03, PA10, PA11, PA12, PA13,
        PA20, PA21, PA22, PA23, PA30, PA31, PA32, PA33;
    f4v PB00, PB01, PB02, PB03, PB10, PB11, PB12, PB13,
        PB20, PB21, PB22, PB23, PB30, PB31, PB32, PB33;

    int t = 1;
    if (lenm1 > 0) {
        LOADSET(PA, 1);
        while (t + 8 <= L) {              // full chunks of 8 steps
            LOADSET(PB, t + 4);
            WAITSET_N(PA, 16);            // PA arrived (PB still in flight)
            STEP(PA, 0, ); STEP(PA, 1, ); STEP(PA, 2, ); STEP(PA, 3, );
            LOADSET(PA, t + 8);
            WAITSET_N(PB, 16);
            STEP(PB, 0, ); STEP(PB, 1, ); STEP(PB, 2, );
            STEP(PB, 3, RESCALE);
            t += 8;
        }
        const int rem = L - t;            // 0..7 remaining steps (uniform)
        if (rem > 0) {
            LOADSET(PB, t + 4);           // clamped rows; extras unused
            WAITSET_N(PA, 16);
            /*            */ STEP(PA, 0, );
            if (rem > 1) { STEP(PA, 1, ); }
            if (rem > 2) { STEP(PA, 2, ); }
            if (rem > 3) { STEP(PA, 3, ); }
            if (rem > 4) { WAITSET_N(PB, 0);
                           STEP(PB, 0, ); }
            if (rem > 5) { STEP(PB, 1, ); }
            if (rem > 6) { STEP(PB, 2, ); }
        }
    }

    // Final LSE: sum this lane's 16 rows + across the 4 gq groups.
    {
        const f4v sv = (u0 + u1) + (u2 + u3);
        float s = (sv[0] + sv[1]) + (sv[2] + sv[3]);
        s += __shfl_xor(s, 16, 64);
        s += __shfl_xor(s, 32, 64);
        const float res = CC + GBIAS * (float)lenm1 + __logf(s);
        if (lane == 0) out[b] = res;
    }
    asm volatile("s_waitcnt vmcnt(0)" ::: "memory");  // drain stragglers
}

extern "C" void kernel_launch(void* const* d_in, const int* in_sizes, int n_in,
                              void* d_out, int out_size, void* d_ws, size_t ws_size,
                              hipStream_t stream)
{
    const float* feats    = (const float*)d_in[0];
    const float* trans    = (const float*)d_in[1];
    const int*   seq_lens = (const int*)d_in[2];
    float*       out      = (float*)d_out;

    crf_forward_kernel<<<dim3(CRF_B), dim3(64), 0, stream>>>(
        feats, trans, seq_lens, out);
}